// Round 1
// baseline (93.566 us; speedup 1.0000x reference)
//
#include <hip/hip_runtime.h>
#include <stdint.h>

#define IN_C 64
#define HH 256
#define WW 256
#define OUT_C 128
#define OH 254
#define OW 254
#define OHW (OH * OW)

#define XR 4     // staged input rows (2 out rows + 2 halo)
#define XW 66    // staged input width (64 + 2 halo)
#define CPAD 72  // padded channel stride: 16B-aligned rows + bank spread

typedef __attribute__((ext_vector_type(4))) float f32x4;
typedef __attribute__((ext_vector_type(8))) __bf16 bf16x8;

__device__ __forceinline__ unsigned short f2bf(float f) {
  union { float f; unsigned u; } v; v.f = f;
  unsigned r = v.u + 0x7FFFu + ((v.u >> 16) & 1u);  // RNE (inputs are finite/normal)
  return (unsigned short)(r >> 16);
}

__device__ __forceinline__ void async_lds16(const void* g, void* l) {
  __builtin_amdgcn_global_load_lds(
      (const __attribute__((address_space(1))) unsigned int*)g,
      (__attribute__((address_space(3))) unsigned int*)l, 16, 0, 0);
}

// Pre-shuffle weights into fragment-ordered bf16:
// wt[tap][ch][mt][lane][j] = bf16( W[o = mt*16 + (lane&15)][c = ch*32 + (lane>>4)*8 + j][ky][kx] )
// so per-tap 16KB is a verbatim global_load_lds copy and A-frag reads are lane-sequential b128.
__global__ void prep_w(const float* __restrict__ w, unsigned short* __restrict__ wt) {
  const int idx = blockIdx.x * 256 + threadIdx.x;
  if (idx >= 9 * 8192) return;
  const int j    = idx & 7;
  const int lane = (idx >> 3) & 63;
  const int mt   = (idx >> 9) & 7;
  const int ch   = (idx >> 12) & 1;
  const int tap  = idx >> 13;
  const int o = mt * 16 + (lane & 15);
  const int c = ch * 32 + (lane >> 4) * 8 + j;
  wt[idx] = f2bf(w[(o * IN_C + c) * 9 + tap]);
}

__global__ __launch_bounds__(256) void conv_mfma(
    const float* __restrict__ x, const unsigned short* __restrict__ wt,
    const float* __restrict__ bias, float* __restrict__ out) {
  // One tap of A (fragment-ordered, straight copy target): [ch][mt][lane][8]
  __shared__ __align__(16) unsigned short As[2 * 8 * 64 * 8];   // 16384 B
  // Transposed input tile: Xs[r][xx][c], c contiguous
  __shared__ __align__(16) unsigned short Xs[XR * XW * CPAD];   // 38016 B
  __shared__ float Bias[OUT_C];                                 // 512 B

  const int tid  = threadIdx.x;
  const int wave = tid >> 6;
  const int lane = tid & 63;
  const int x0 = blockIdx.x * 64;   // 0,64,128,192 (last tile masks stores >= 254)
  const int y0 = blockIdx.y * 2;

  if (tid < OUT_C) Bias[tid] = bias[tid];

  // ---- stage Xs: Xs[r][xx][c] = bf16(x[c][y0+r][x0+xx])
  {
    const int sc = tid >> 2;  // 0..63 : channel
    const int sq = tid & 3;   // 0..3  : 16B sub-chunk -> 4-lane 64B coalesced segments
    const float* base = x + sc * (HH * WW);
#pragma unroll
    for (int r = 0; r < XR; ++r) {
      const float* row = base + (y0 + r) * WW + x0;
#pragma unroll
      for (int xq = 0; xq < 4; ++xq) {
        const int xx = xq * 16 + sq * 4;
        const f32x4 v = *(const f32x4*)(row + xx);
#pragma unroll
        for (int i = 0; i < 4; ++i)
          Xs[(r * XW + xx + i) * CPAD + sc] = f2bf(v[i]);
      }
    }
    // tail halo xx = 64, 65 (clamped reads: only feed masked out-columns on last tile)
    if (tid < 128) {
      const int c = tid & 63;
      const int xxt = 64 + (tid >> 6);
      int xg = x0 + xxt;
      if (xg > WW - 1) xg = WW - 1;
#pragma unroll
      for (int r = 0; r < XR; ++r)
        Xs[(r * XW + xxt) * CPAD + c] = f2bf(x[c * (HH * WW) + (y0 + r) * WW + xg]);
    }
  }

  // ---- async-stage As for tap 0 (verbatim 16KB copy, width=16)
  {
    const char* wtap = (const char*)wt;  // tap 0
#pragma unroll
    for (int i = 0; i < 4; ++i) {
      const int off = (wave * 4 + i) * 1024;
      async_lds16(wtap + off + lane * 16, (char*)As + off);
    }
  }
  __syncthreads();  // drains lgkm (Xs writes) + vmcnt (As copy)

  const int mhalf = wave & 1;   // which half of the 128 out-channels
  const int nhalf = wave >> 1;  // which of the 2 output rows
  const int nlane = lane & 15;
  const int quad  = lane >> 4;

  f32x4 acc[4][4];
#pragma unroll
  for (int mt = 0; mt < 4; ++mt)
#pragma unroll
    for (int nt = 0; nt < 4; ++nt)
      acc[mt][nt] = f32x4{0.f, 0.f, 0.f, 0.f};

#pragma unroll 1
  for (int tap = 0; tap < 9; ++tap) {
    const int ky = tap / 3;
    const int kx = tap - ky * 3;
    const int r = nhalf + ky;
#pragma unroll
    for (int ch = 0; ch < 2; ++ch) {
      bf16x8 af[4], bfr[4];
#pragma unroll
      for (int mt = 0; mt < 4; ++mt)
        af[mt] = *(const bf16x8*)&As[((ch * 8 + mhalf * 4 + mt) * 64 + lane) * 8];
#pragma unroll
      for (int nt = 0; nt < 4; ++nt)
        bfr[nt] = *(const bf16x8*)&Xs[(r * XW + kx + nt * 16 + nlane) * CPAD + ch * 32 + quad * 8];
#pragma unroll
      for (int mt = 0; mt < 4; ++mt)
#pragma unroll
        for (int nt = 0; nt < 4; ++nt)
          acc[mt][nt] = __builtin_amdgcn_mfma_f32_16x16x32_bf16(af[mt], bfr[nt], acc[mt][nt], 0, 0, 0);
    }
    if (tap < 8) {
      __syncthreads();  // all waves done reading As[tap]
      const char* wtap = (const char*)(wt + (tap + 1) * 8192);
#pragma unroll
      for (int i = 0; i < 4; ++i) {
        const int off = (wave * 4 + i) * 1024;
        async_lds16(wtap + off + lane * 16, (char*)As + off);
      }
      __syncthreads();  // As[tap+1] landed (barrier drains vmcnt)
    }
  }

  // ---- epilogue: C/D layout col = lane&15 (pixel), row = quad*4 + reg (out-ch)
  const int y = y0 + nhalf;
#pragma unroll
  for (int mt = 0; mt < 4; ++mt) {
    const int obase = (mhalf * 4 + mt) * 16 + quad * 4;
#pragma unroll
    for (int nt = 0; nt < 4; ++nt) {
      const int xc = x0 + nt * 16 + nlane;
      if (xc < OW) {
        float* dst = out + obase * OHW + y * OW + xc;
#pragma unroll
        for (int reg = 0; reg < 4; ++reg)
          dst[reg * OHW] = acc[mt][nt][reg] + Bias[obase + reg];
      }
    }
  }
}

extern "C" void kernel_launch(void* const* d_in, const int* in_sizes, int n_in,
                              void* d_out, int out_size, void* d_ws, size_t ws_size,
                              hipStream_t stream) {
  const float* x = (const float*)d_in[0];
  const float* w = (const float*)d_in[1];
  const float* b = (const float*)d_in[2];
  float* out = (float*)d_out;
  unsigned short* wt = (unsigned short*)d_ws;  // 147456 B of fragment-ordered bf16 weights

  prep_w<<<dim3(288), dim3(256), 0, stream>>>(w, wt);
  conv_mfma<<<dim3(4, 127), dim3(256), 0, stream>>>(x, wt, b, out);
}